// Round 6
// baseline (605.994 us; speedup 1.0000x reference)
//
#include <hip/hip_runtime.h>

// h_t = alpha_t*h_{t-1} + x_t along S per (b,d). B=4, S=8192, D=1024, fp32.
// Cooperative single-load scan, round-6 revision: 4 blocks/CU co-resident
// (grid=1024, launch_bounds(256,4) -> VGPR<=128, 16 waves/CU) to fix the
// round-5 rate limit (1 block/CU = 4 waves/CU = 1.9 TB/s effective).
//   Block (b,c) owns chunk c (L=32 rows); thread owns 4 channels (one float4 col).
//   Pass A: stream chunk double-buffered (G=4 rows/group), aggregate (X,A), publish.
//   gridbar; 16 blocks sweep the 256-chunk carry chains (1 thread/channel, 8-deep);
//   gridbar; Pass B: re-read chunk (L3-hot), seed with prefix, NT-store output.
constexpr int B    = 4;
constexpr int S    = 8192;
constexpr int D    = 1024;
constexpr int CB   = 256;        // chunks per batch
constexpr int L    = S / CB;     // 32 rows per chunk
constexpr int D4   = D / 4;      // 256 float4 per row = one 256-thread block
constexpr int NBLK = B * CB;     // 1024 blocks = 4 per CU (co-resident by construction)
constexpr int G    = 4;          // rows per load group (keeps VGPR under the 128 cap)
constexpr int NG   = L / G;      // 8 groups per chunk

typedef float nt_float4 __attribute__((ext_vector_type(4)));

// Agent-scope (cross-XCD coherent) accessors for shared state.
__device__ __forceinline__ void ast(float* p, float v) {
    __hip_atomic_store(p, v, __ATOMIC_RELAXED, __HIP_MEMORY_SCOPE_AGENT);
}
__device__ __forceinline__ float ald(const float* p) {
    return __hip_atomic_load(p, __ATOMIC_RELAXED, __HIP_MEMORY_SCOPE_AGENT);
}

// Software grid barrier: all NBLK blocks co-resident (4/CU x 256 CU = 1024).
__device__ __forceinline__ void gridbar(int* bar) {
    __syncthreads();                       // drains vmcnt: block's stores complete first
    if (threadIdx.x == 0) {
        __hip_atomic_fetch_add(bar, 1, __ATOMIC_ACQ_REL, __HIP_MEMORY_SCOPE_AGENT);
        while (__hip_atomic_load(bar, __ATOMIC_RELAXED, __HIP_MEMORY_SCOPE_AGENT) < NBLK)
            __builtin_amdgcn_s_sleep(2);
        __threadfence();                   // acquire: invalidate stale L1 lines
    }
    __syncthreads();
}

__device__ __forceinline__ void issue_grp(const float4* __restrict__ x,
                                          const float4* __restrict__ a,
                                          long o, float4 (&bx)[G], float4 (&ba)[G]) {
    #pragma unroll
    for (int j = 0; j < G; ++j) {
        bx[j] = x[o + (long)j * D4];
        ba[j] = a[o + (long)j * D4];
    }
}

__global__ __launch_bounds__(256, 4) void scan_coop(const float4* __restrict__ x,
                                                    const float4* __restrict__ a,
                                                    float4* __restrict__ out,
                                                    float* __restrict__ Xagg,
                                                    float* __restrict__ Aagg,
                                                    float* __restrict__ Pref,
                                                    int* __restrict__ bars) {
    const int t   = threadIdx.x;
    const int bid = blockIdx.x;
    const int b   = bid >> 8;              // batch (CB=256)
    const int c   = bid & (CB - 1);        // chunk
    const long base = ((long)(b * S + c * L)) * D4 + t;

    float4 bx0[G], ba0[G], bx1[G], ba1[G];

    // ---------------- Pass A: stream chunk, compute (X, A) aggregate ----------------
    float4 X = {0.f, 0.f, 0.f, 0.f};
    float4 A = {1.f, 1.f, 1.f, 1.f};
    issue_grp(x, a, base, bx0, ba0);
    #pragma unroll
    for (int g = 0; g < NG; g += 2) {
        issue_grp(x, a, base + (long)(g + 1) * G * D4, bx1, ba1);   // g+1 <= NG-1
        #pragma unroll
        for (int j = 0; j < G; ++j) {
            X.x = fmaf(ba0[j].x, X.x, bx0[j].x); A.x *= ba0[j].x;
            X.y = fmaf(ba0[j].y, X.y, bx0[j].y); A.y *= ba0[j].y;
            X.z = fmaf(ba0[j].z, X.z, bx0[j].z); A.z *= ba0[j].z;
            X.w = fmaf(ba0[j].w, X.w, bx0[j].w); A.w *= ba0[j].w;
        }
        if (g + 2 < NG) issue_grp(x, a, base + (long)(g + 2) * G * D4, bx0, ba0);
        #pragma unroll
        for (int j = 0; j < G; ++j) {
            X.x = fmaf(ba1[j].x, X.x, bx1[j].x); A.x *= ba1[j].x;
            X.y = fmaf(ba1[j].y, X.y, bx1[j].y); A.y *= ba1[j].y;
            X.z = fmaf(ba1[j].z, X.z, bx1[j].z); A.z *= ba1[j].z;
            X.w = fmaf(ba1[j].w, X.w, bx1[j].w); A.w *= ba1[j].w;
        }
    }
    {   // publish aggregates: layout [r][D], r = bid, channels d = 4t..4t+3
        float* Xp = Xagg + (long)bid * D + 4 * t;
        float* Ap = Aagg + (long)bid * D + 4 * t;
        ast(Xp + 0, X.x); ast(Xp + 1, X.y); ast(Xp + 2, X.z); ast(Xp + 3, X.w);
        ast(Ap + 0, A.x); ast(Ap + 1, A.y); ast(Ap + 2, A.z); ast(Ap + 3, A.w);
    }

    gridbar(bars + 0);

    // ---------------- Sweep: 16 blocks, 1 thread per (batch, channel) ----------------
    if (bid < 16) {
        const int gg = bid * 256 + t;      // 0..4095
        const int sb = gg >> 10;           // batch
        const int d  = gg & (D - 1);       // channel
        const float* Xp = Xagg + (long)sb * CB * D + d;   // stride D along chunks
        const float* Ap = Aagg + (long)sb * CB * D + d;
        float*       Pp = Pref + (long)sb * CB * D + d;
        float carry = 0.f;
        for (int cc = 0; cc < CB; cc += 8) {
            float xv[8], av[8];
            #pragma unroll
            for (int j = 0; j < 8; ++j) {  // 16 independent loads in flight
                xv[j] = ald(Xp + (long)(cc + j) * D);
                av[j] = ald(Ap + (long)(cc + j) * D);
            }
            #pragma unroll
            for (int j = 0; j < 8; ++j) {  // serial part: 8 fmas
                ast(Pp + (long)(cc + j) * D, carry);      // exclusive prefix
                carry = fmaf(av[j], carry, xv[j]);
            }
        }
    }

    gridbar(bars + 1);

    // ---------------- Pass B: re-read chunk (L3-hot), emit with carry ----------------
    float4 h;
    {
        const float* Pp = Pref + (long)bid * D + 4 * t;
        h.x = ald(Pp + 0); h.y = ald(Pp + 1); h.z = ald(Pp + 2); h.w = ald(Pp + 3);
    }
    nt_float4* ntout = (nt_float4*)out;
    issue_grp(x, a, base, bx0, ba0);
    #pragma unroll
    for (int g = 0; g < NG; g += 2) {
        issue_grp(x, a, base + (long)(g + 1) * G * D4, bx1, ba1);
        #pragma unroll
        for (int j = 0; j < G; ++j) {
            h.x = fmaf(ba0[j].x, h.x, bx0[j].x);
            h.y = fmaf(ba0[j].y, h.y, bx0[j].y);
            h.z = fmaf(ba0[j].z, h.z, bx0[j].z);
            h.w = fmaf(ba0[j].w, h.w, bx0[j].w);
            nt_float4 hv = {h.x, h.y, h.z, h.w};
            __builtin_nontemporal_store(hv, &ntout[base + (long)(g * G + j) * D4]);
        }
        if (g + 2 < NG) issue_grp(x, a, base + (long)(g + 2) * G * D4, bx0, ba0);
        #pragma unroll
        for (int j = 0; j < G; ++j) {
            h.x = fmaf(ba1[j].x, h.x, bx1[j].x);
            h.y = fmaf(ba1[j].y, h.y, bx1[j].y);
            h.z = fmaf(ba1[j].z, h.z, bx1[j].z);
            h.w = fmaf(ba1[j].w, h.w, bx1[j].w);
            nt_float4 hv = {h.x, h.y, h.z, h.w};
            __builtin_nontemporal_store(hv, &ntout[base + (long)((g + 1) * G + j) * D4]);
        }
    }
}

extern "C" void kernel_launch(void* const* d_in, const int* in_sizes, int n_in,
                              void* d_out, int out_size, void* d_ws, size_t ws_size,
                              hipStream_t stream) {
    const float4* x = (const float4*)d_in[0];
    const float4* a = (const float4*)d_in[1];
    float4* out = (float4*)d_out;

    // Workspace: [bars 4KB] | Xagg 4MB | Aagg 4MB | Pref 4MB  (~12 MiB)
    char* ws = (char*)d_ws;
    int*   bars = (int*)ws;
    float* Xagg = (float*)(ws + 4096);
    float* Aagg = Xagg + (size_t)NBLK * D;
    float* Pref = Aagg + (size_t)NBLK * D;

    hipMemsetAsync(ws, 0, 4096, stream);   // reset barrier counters (graph-capturable)
    scan_coop<<<dim3(NBLK), 256, 0, stream>>>(x, a, out, Xagg, Aagg, Pref, bars);
}

// Round 7
// 444.191 us; speedup vs baseline: 1.3643x; 1.3643x over previous
//
#include <hip/hip_runtime.h>

// h_t = alpha_t*h_{t-1} + x_t along S per (b,d). B=4, S=8192, D=1024, fp32.
// Round-7: r5 cooperative structure (256 blocks, gridbar, sweep) but 512
// threads/block = 8 waves/CU at full VGPR budget (launch_bounds(512,1) ->
// 256 VGPR/thread). Tests whether the ~2.8 TB/s logical-rate cap is
// TLP-limited (r5: 4 waves/CU) or structural.
//   Block (b,c) owns chunk c (L=128 rows); two 256-thread TEAMS take 64 rows
//   each. Team aggregates combine via LDS (ordered). Sweep identical to r5.
//   Pass B: team0 seeds with block carry, team1 with X0 + A0*carry (LDS).
constexpr int B    = 4;
constexpr int S    = 8192;
constexpr int D    = 1024;
constexpr int CB   = 64;         // chunks per batch
constexpr int L    = S / CB;     // 128 rows per chunk
constexpr int HL   = L / 2;      // 64 rows per team
constexpr int D4   = D / 4;      // 256 float4 per row
constexpr int NBLK = B * CB;     // 256 blocks = 1 per CU (co-resident)
constexpr int G    = 8;          // rows per load group
constexpr int NG   = HL / G;     // 8 groups per team

typedef float nt_float4 __attribute__((ext_vector_type(4)));

__device__ __forceinline__ void ast(float* p, float v) {
    __hip_atomic_store(p, v, __ATOMIC_RELAXED, __HIP_MEMORY_SCOPE_AGENT);
}
__device__ __forceinline__ float ald(const float* p) {
    return __hip_atomic_load(p, __ATOMIC_RELAXED, __HIP_MEMORY_SCOPE_AGENT);
}

// Software grid barrier: all NBLK blocks co-resident (1/CU).
__device__ __forceinline__ void gridbar(int* bar) {
    __syncthreads();                       // drains vmcnt for the whole block first
    if (threadIdx.x == 0) {
        __hip_atomic_fetch_add(bar, 1, __ATOMIC_ACQ_REL, __HIP_MEMORY_SCOPE_AGENT);
        while (__hip_atomic_load(bar, __ATOMIC_RELAXED, __HIP_MEMORY_SCOPE_AGENT) < NBLK)
            __builtin_amdgcn_s_sleep(2);
        __threadfence();                   // acquire
    }
    __syncthreads();
}

__device__ __forceinline__ void issue_grp(const float4* __restrict__ x,
                                          const float4* __restrict__ a,
                                          long o, float4 (&bx)[G], float4 (&ba)[G]) {
    #pragma unroll
    for (int j = 0; j < G; ++j) {
        bx[j] = x[o + (long)j * D4];
        ba[j] = a[o + (long)j * D4];
    }
}

__global__ __launch_bounds__(512, 1) void scan_coop(const float4* __restrict__ x,
                                                    const float4* __restrict__ a,
                                                    float4* __restrict__ out,
                                                    float* __restrict__ Xagg,
                                                    float* __restrict__ Aagg,
                                                    float* __restrict__ Pref,
                                                    int* __restrict__ bars) {
    const int t    = threadIdx.x;
    const int team = t >> 8;               // 0: rows 0..63, 1: rows 64..127
    const int u    = t & 255;              // lane within team = float4 column
    const int bid  = blockIdx.x;
    const int b    = bid >> 6;             // batch (CB=64)
    const int c    = bid & (CB - 1);       // chunk
    const long base = ((long)(b * S + c * L + team * HL)) * D4 + u;

    __shared__ float4 lX0[256], lA0[256];  // team0 sub-aggregate (8 KB)

    float4 bx0[G], ba0[G], bx1[G], ba1[G];

    // ---------------- Pass A: each team streams its 64 rows ----------------
    float4 X = {0.f, 0.f, 0.f, 0.f};
    float4 A = {1.f, 1.f, 1.f, 1.f};
    issue_grp(x, a, base, bx0, ba0);
    #pragma unroll
    for (int g = 0; g < NG; g += 2) {
        issue_grp(x, a, base + (long)(g + 1) * G * D4, bx1, ba1);
        #pragma unroll
        for (int j = 0; j < G; ++j) {
            X.x = fmaf(ba0[j].x, X.x, bx0[j].x); A.x *= ba0[j].x;
            X.y = fmaf(ba0[j].y, X.y, bx0[j].y); A.y *= ba0[j].y;
            X.z = fmaf(ba0[j].z, X.z, bx0[j].z); A.z *= ba0[j].z;
            X.w = fmaf(ba0[j].w, X.w, bx0[j].w); A.w *= ba0[j].w;
        }
        if (g + 2 < NG) issue_grp(x, a, base + (long)(g + 2) * G * D4, bx0, ba0);
        #pragma unroll
        for (int j = 0; j < G; ++j) {
            X.x = fmaf(ba1[j].x, X.x, bx1[j].x); A.x *= ba1[j].x;
            X.y = fmaf(ba1[j].y, X.y, bx1[j].y); A.y *= ba1[j].y;
            X.z = fmaf(ba1[j].z, X.z, bx1[j].z); A.z *= ba1[j].z;
            X.w = fmaf(ba1[j].w, X.w, bx1[j].w); A.w *= ba1[j].w;
        }
    }
    if (team == 0) { lX0[u] = X; lA0[u] = A; }
    __syncthreads();
    if (team == 1) {
        // Combined chunk aggregate: second∘first => Xc = X1 + A1*X0, Ac = A1*A0.
        const float4 X0 = lX0[u], A0 = lA0[u];
        float4 Xc, Ac;
        Xc.x = fmaf(A.x, X0.x, X.x); Ac.x = A.x * A0.x;
        Xc.y = fmaf(A.y, X0.y, X.y); Ac.y = A.y * A0.y;
        Xc.z = fmaf(A.z, X0.z, X.z); Ac.z = A.z * A0.z;
        Xc.w = fmaf(A.w, X0.w, X.w); Ac.w = A.w * A0.w;
        float* Xp = Xagg + (long)bid * D + 4 * u;
        float* Ap = Aagg + (long)bid * D + 4 * u;
        ast(Xp + 0, Xc.x); ast(Xp + 1, Xc.y); ast(Xp + 2, Xc.z); ast(Xp + 3, Xc.w);
        ast(Ap + 0, Ac.x); ast(Ap + 1, Ac.y); ast(Ap + 2, Ac.z); ast(Ap + 3, Ac.w);
    }

    gridbar(bars + 0);

    // ---------------- Sweep: 16 blocks, 1 thread per (batch, channel) ----------------
    if (bid < 16 && t < 256) {
        const int gg = bid * 256 + t;      // 0..4095
        const int sb = gg >> 10;           // batch
        const int d  = gg & (D - 1);       // channel
        const float* Xp = Xagg + (long)sb * CB * D + d;
        const float* Ap = Aagg + (long)sb * CB * D + d;
        float*       Pp = Pref + (long)sb * CB * D + d;
        float carry = 0.f;
        for (int cc = 0; cc < CB; cc += 8) {
            float xv[8], av[8];
            #pragma unroll
            for (int j = 0; j < 8; ++j) {
                xv[j] = ald(Xp + (long)(cc + j) * D);
                av[j] = ald(Ap + (long)(cc + j) * D);
            }
            #pragma unroll
            for (int j = 0; j < 8; ++j) {
                ast(Pp + (long)(cc + j) * D, carry);      // exclusive prefix
                carry = fmaf(av[j], carry, xv[j]);
            }
        }
    }

    gridbar(bars + 1);

    // ---------------- Pass B: re-read (L3-hot), emit with per-team carry ----------------
    float4 h;
    {
        const float* Pp = Pref + (long)bid * D + 4 * u;
        float4 cb;
        cb.x = ald(Pp + 0); cb.y = ald(Pp + 1); cb.z = ald(Pp + 2); cb.w = ald(Pp + 3);
        if (team == 0) h = cb;
        else {                              // carry entering row 64 = X0 + A0*carry
            h.x = fmaf(lA0[u].x, cb.x, lX0[u].x);
            h.y = fmaf(lA0[u].y, cb.y, lX0[u].y);
            h.z = fmaf(lA0[u].z, cb.z, lX0[u].z);
            h.w = fmaf(lA0[u].w, cb.w, lX0[u].w);
        }
    }
    nt_float4* ntout = (nt_float4*)out;
    issue_grp(x, a, base, bx0, ba0);
    #pragma unroll
    for (int g = 0; g < NG; g += 2) {
        issue_grp(x, a, base + (long)(g + 1) * G * D4, bx1, ba1);
        #pragma unroll
        for (int j = 0; j < G; ++j) {
            h.x = fmaf(ba0[j].x, h.x, bx0[j].x);
            h.y = fmaf(ba0[j].y, h.y, bx0[j].y);
            h.z = fmaf(ba0[j].z, h.z, bx0[j].z);
            h.w = fmaf(ba0[j].w, h.w, bx0[j].w);
            nt_float4 hv = {h.x, h.y, h.z, h.w};
            __builtin_nontemporal_store(hv, &ntout[base + (long)(g * G + j) * D4]);
        }
        if (g + 2 < NG) issue_grp(x, a, base + (long)(g + 2) * G * D4, bx0, ba0);
        #pragma unroll
        for (int j = 0; j < G; ++j) {
            h.x = fmaf(ba1[j].x, h.x, bx1[j].x);
            h.y = fmaf(ba1[j].y, h.y, bx1[j].y);
            h.z = fmaf(ba1[j].z, h.z, bx1[j].z);
            h.w = fmaf(ba1[j].w, h.w, bx1[j].w);
            nt_float4 hv = {h.x, h.y, h.z, h.w};
            __builtin_nontemporal_store(hv, &ntout[base + (long)((g + 1) * G + j) * D4]);
        }
    }
}

extern "C" void kernel_launch(void* const* d_in, const int* in_sizes, int n_in,
                              void* d_out, int out_size, void* d_ws, size_t ws_size,
                              hipStream_t stream) {
    const float4* x = (const float4*)d_in[0];
    const float4* a = (const float4*)d_in[1];
    float4* out = (float4*)d_out;

    // Workspace: [bars 4KB] | Xagg 1MB | Aagg 1MB | Pref 1MB
    char* ws = (char*)d_ws;
    int*   bars = (int*)ws;
    float* Xagg = (float*)(ws + 4096);
    float* Aagg = Xagg + (size_t)NBLK * D;
    float* Pref = Aagg + (size_t)NBLK * D;

    hipMemsetAsync(ws, 0, 4096, stream);   // reset barrier counters (graph-capturable)
    scan_coop<<<dim3(NBLK), 512, 0, stream>>>(x, a, out, Xagg, Aagg, Pref, bars);
}